// Round 11
// baseline (182.069 us; speedup 1.0000x reference)
//
#include <hip/hip_runtime.h>
#include <math.h>

#define DIM 1024
#define NH 16
#define NKV 4
#define HD 64
#define WINDOW 16
#define EPS 0.01f

typedef __bf16 bf16_t;
typedef bf16_t bf16x8 __attribute__((ext_vector_type(8)));
typedef bf16_t bf16x4 __attribute__((ext_vector_type(4)));
typedef float f32x4 __attribute__((ext_vector_type(4)));

// ---------------- fused fp32 -> bf16 conversion of all 5 tensors ----------------
__global__ __launch_bounds__(256) void f2bf_all(const float* __restrict__ x,
                                                const float* __restrict__ wq,
                                                const float* __restrict__ wk,
                                                const float* __restrict__ wv,
                                                const float* __restrict__ wo,
                                                bf16_t* __restrict__ xb,
                                                bf16_t* __restrict__ wqkvb,
                                                bf16_t* __restrict__ wob) {
  int i = blockIdx.x * blockDim.x + threadIdx.x;
  const float* src;
  bf16_t* dst;
  int off;
  if (i < 1048576) { src = x; dst = xb; off = i; }
  else if (i < 1310720) { src = wq; dst = wqkvb; off = i - 1048576; }
  else if (i < 1376256) { src = wk; dst = wqkvb + (size_t)1024 * DIM; off = i - 1310720; }
  else if (i < 1441792) { src = wv; dst = wqkvb + (size_t)1280 * DIM; off = i - 1376256; }
  else { src = wo; dst = wob; off = i - 1441792; }
  float4 f = ((const float4*)src)[off];
  bf16x4 o = {(bf16_t)f.x, (bf16_t)f.y, (bf16_t)f.z, (bf16_t)f.w};
  ((bf16x4*)dst)[off] = o;
}

// ========== 128(M)x64(N), BK=64 GEMM: A via dbuf LDS, B direct-from-global ====
// B-fragments (n=col0+ni*16+lcol, k contiguous 16B) load straight from the
// row-major [N,K] weight matrix into registers, prefetched one K-iter ahead:
// issued right after the barrier, covered by the MFMA phase, complete by the
// next barrier's drain. Removes 8/12 per-wave ds_read_b128 (all 4 waves read
// identical B) and the B DMA + LDS writes. LDS holds only A (16 KB x 2 bufs).
// A swizzle: row r, slot s holds chunk kc=(s-r)&7; reader slot=(kc+r)&7.
// XCD-affinity: xcd = id&7 owns whole 128-row A-panels (neutral but free).

#define GEMM_STAGE_A(buf, Ag)                                                   \
  {                                                                             \
    _Pragma("unroll")                                                           \
    for (int it = 0; it < 4; it++) {                                            \
      int c = it * 256 + t;                                                     \
      int r = c >> 3;                                                           \
      int kc = ((c & 7) - r) & 7;                                               \
      __builtin_amdgcn_global_load_lds(                                         \
          (const __attribute__((address_space(1))) void*)((Ag) + (size_t)r * K + kc * 8), \
          (__attribute__((address_space(3))) void*)(As[buf] + c * 8), 16, 0, 0); \
    }                                                                           \
  }

#define LOAD_BFR(dst, kbase)                                                    \
  {                                                                             \
    _Pragma("unroll")                                                           \
    for (int h = 0; h < 2; h++)                                                 \
      _Pragma("unroll")                                                         \
      for (int ni = 0; ni < 4; ni++)                                            \
        dst[h][ni] = *(const bf16x8*)(Bfrag0 + (size_t)ni * 16 * K + (h * 32) + (kbase)); \
  }

#define GEMM_DBUF_LOOP(Aptr, Bptr)                                              \
  const bf16_t* Abase = Aptr + (size_t)row0 * K;                                \
  const bf16_t* Bfrag0 = Bptr + (size_t)(col0 + lcol) * K + lquad * 8;          \
  bf16x8 bfrC[2][4], bfrN[2][4];                                                \
  GEMM_STAGE_A(0, Abase)                                                        \
  LOAD_BFR(bfrN, 0)                                                             \
  {                                                                             \
    const int nIter = K >> 6;                                                   \
    for (int ki = 0; ki < nIter; ki++) {                                        \
      __syncthreads();                                                          \
      if (ki + 1 < nIter) {                                                     \
        GEMM_STAGE_A((ki + 1) & 1, Abase + (ki + 1) * 64)                       \
      }                                                                         \
      _Pragma("unroll")                                                         \
      for (int h = 0; h < 2; h++)                                               \
        _Pragma("unroll")                                                       \
        for (int ni = 0; ni < 4; ni++) bfrC[h][ni] = bfrN[h][ni];               \
      if (ki + 1 < nIter) LOAD_BFR(bfrN, (ki + 1) * 64)                         \
      const bf16_t* Ab = As[ki & 1];                                            \
      _Pragma("unroll")                                                         \
      for (int h = 0; h < 2; h++) {                                             \
        bf16x8 af[2];                                                           \
        _Pragma("unroll")                                                       \
        for (int mi = 0; mi < 2; mi++) af[mi] = *(const bf16x8*)(Ab + aoff[h][mi]); \
        _Pragma("unroll")                                                       \
        for (int mi = 0; mi < 2; mi++)                                          \
          _Pragma("unroll")                                                     \
          for (int ni = 0; ni < 4; ni++)                                        \
            acc[mi][ni] = __builtin_amdgcn_mfma_f32_16x16x32_bf16(af[mi], bfrC[h][ni], \
                                                                  acc[mi][ni], 0, 0, 0); \
      }                                                                         \
      __syncthreads();                                                          \
    }                                                                           \
  }

// NBX = N/64 column blocks; BYX = (M/128)/8 row-panels per XCD
#define GEMM_PROLOGUE(NBX, BYX)                                                 \
  const int t = threadIdx.x;                                                    \
  const int lane = t & 63;                                                      \
  const int wid = t >> 6;                                                       \
  const int xcd = blockIdx.x & 7;                                               \
  const int jj = blockIdx.x >> 3;                                               \
  const int bx = jj % (NBX);                                                    \
  const int row0 = (xcd * (BYX) + jj / (NBX)) * 128;                            \
  const int col0 = bx * 64;                                                     \
  const int wm = wid * 32;                                                      \
  const int lquad = lane >> 4;                                                  \
  const int lcol = lane & 15;                                                   \
  int aoff[2][2];                                                               \
  _Pragma("unroll")                                                             \
  for (int h = 0; h < 2; h++) {                                                 \
    _Pragma("unroll")                                                           \
    for (int mi = 0; mi < 2; mi++) {                                            \
      int r = wm + mi * 16 + lcol;                                              \
      aoff[h][mi] = r * 64 + (((h * 4 + lquad) + r) & 7) * 8;                   \
    }                                                                           \
  }                                                                             \
  f32x4 acc[2][4] = {};

// ---------------- QKV GEMM with fused per-head RMSNorm epilogue ----------------
__global__ __launch_bounds__(256) void gemm_qkv_rms(const bf16_t* __restrict__ A,
                                                    const bf16_t* __restrict__ B,
                                                    bf16_t* __restrict__ C,
                                                    const float* __restrict__ qw,
                                                    const float* __restrict__ kw,
                                                    int M, int N, int K) {
  __shared__ bf16_t As[2][128 * 64];
  GEMM_PROLOGUE(24, 4)
  GEMM_DBUF_LOOP(A, B)

  // ---- fused RMSNorm epilogue: block's 64 cols == one head, wave-local rows
  const int hcol = bx;                   // 0..23
  const bool isv = (hcol >= 20);
  float wreg[4];
  if (!isv) {
    const float* wp = (hcol < 16) ? qw : kw;
#pragma unroll
    for (int ni = 0; ni < 4; ni++) wreg[ni] = wp[ni * 16 + lcol];
  }

#pragma unroll
  for (int mi = 0; mi < 2; mi++) {
#pragma unroll
    for (int r = 0; r < 4; r++) {
      float norm = 1.0f;
      if (!isv) {
        float ss = 0.0f;
#pragma unroll
        for (int ni = 0; ni < 4; ni++) ss += acc[mi][ni][r] * acc[mi][ni][r];
#pragma unroll
        for (int off = 8; off >= 1; off >>= 1) ss += __shfl_xor(ss, off);
        norm = rsqrtf(ss * (1.0f / 64.0f) + EPS);
      }
      size_t base = (size_t)(row0 + wm + mi * 16 + lquad * 4 + r) * N + col0 + lcol;
#pragma unroll
      for (int ni = 0; ni < 4; ni++) {
        float v = acc[mi][ni][r] * norm;
        if (!isv) v *= wreg[ni];
        C[base + ni * 16] = (bf16_t)v;
      }
    }
  }
}

// ---------------- bf16 MFMA GEMM (128x64, A-dbuf, B-direct) -------------------
template <typename CT, int NBX, int BYX>
__global__ __launch_bounds__(256) void gemm_bf16(const bf16_t* __restrict__ A,
                                                 const bf16_t* __restrict__ B,
                                                 CT* __restrict__ C,
                                                 int M, int N, int K) {
  __shared__ bf16_t As[2][128 * 64];
  GEMM_PROLOGUE(NBX, BYX)
  GEMM_DBUF_LOOP(A, B)

#pragma unroll
  for (int mi = 0; mi < 2; mi++)
#pragma unroll
    for (int ni = 0; ni < 4; ni++) {
      size_t base = (size_t)(row0 + wm + mi * 16 + lquad * 4) * N + col0 + ni * 16 + lcol;
#pragma unroll
      for (int r = 0; r < 4; r++)
        C[base + (size_t)r * N] = (CT)acc[mi][ni][r];
    }
}

// ---------------- MFMA banded ALiBi attention (shared K/V staging) -----------
#define LKP 72  // K row stride (keys x dims)
#define LVP 40  // VT / P row stride

__global__ __launch_bounds__(1024) void attn_mfma(const bf16_t* __restrict__ qkv,
                                                  bf16_t* __restrict__ y) {
  __shared__ bf16_t Ks[4][32][LKP];    // [kvh][key][dim]
  __shared__ bf16_t VTs[4][64][LVP];   // [kvh][dim][swizzled key]
  __shared__ bf16_t Ps[16][16][LVP];   // [wave][qrow][key]

  const int t = threadIdx.x;
  const int lane = t & 63;
  const int w = t >> 6;                // 0..15 = head
  const int b = blockIdx.x >> 7;
  const int i0loc = (blockIdx.x & 127) << 4;
  const int rowbase = b << 11;
  const int rowg0 = rowbase + i0loc;

  // ---- stage K and V once: thread t handles chunk t (kvh, key, 16B dim-chunk)
  {
    int kvh = t >> 8;
    int key = (t >> 3) & 31;
    int dc = t & 7;
    int jloc = i0loc - 16 + key;
    int rg = rowbase + (jloc < 0 ? 0 : jloc);
    const bf16_t* src = qkv + (size_t)rg * 1536 + 1024 + kvh * 64 + dc * 8;
    bf16x8 kval = *(const bf16x8*)src;
    *(bf16x8*)(&Ks[kvh][key][dc * 8]) = kval;
    bf16x8 vval = *(const bf16x8*)(src + 256);   // V is 256 elems after K
    int kslot = ((key >> 3) ^ (dc & 3)) * 8 + (key & 7);
#pragma unroll
    for (int e = 0; e < 8; e++) VTs[kvh][dc * 8 + e][kslot] = vval[e];
  }
  __syncthreads();

  const int col = lane & 15;
  const int quad = lane >> 4;
  const int h = w;
  const int kvh = w & 3;
  const float slope = exp2f(-0.5f * (float)(h + 1));

  bf16x8 kf[2][2];
#pragma unroll
  for (int kt = 0; kt < 2; kt++)
#pragma unroll
    for (int kc = 0; kc < 2; kc++)
      kf[kt][kc] = *(const bf16x8*)(&Ks[kvh][kt * 16 + col][kc * 32 + quad * 8]);
  bf16x8 vf[4];
#pragma unroll
  for (int nt = 0; nt < 4; nt++) {
    int dim = nt * 16 + col;
    int kchunk = quad ^ ((dim >> 3) & 3);
    vf[nt] = *(const bf16x8*)(&VTs[kvh][dim][kchunk * 8]);
  }

  const bf16_t* qrow = qkv + (size_t)(rowg0 + col) * 1536 + h * 64;
  bf16x8 qf0 = *(const bf16x8*)(qrow + quad * 8);
  bf16x8 qf1 = *(const bf16x8*)(qrow + 32 + quad * 8);

  f32x4 s0 = {}, s1 = {};
  s0 = __builtin_amdgcn_mfma_f32_16x16x32_bf16(qf0, kf[0][0], s0, 0, 0, 0);
  s0 = __builtin_amdgcn_mfma_f32_16x16x32_bf16(qf1, kf[0][1], s0, 0, 0, 0);
  s1 = __builtin_amdgcn_mfma_f32_16x16x32_bf16(qf0, kf[1][0], s1, 0, 0, 0);
  s1 = __builtin_amdgcn_mfma_f32_16x16x32_bf16(qf1, kf[1][1], s1, 0, 0, 0);

  const bool t0dead = (i0loc == 0);
  float sc0[4], sc1[4];
#pragma unroll
  for (int r = 0; r < 4; r++) {
    int rel0 = col - 16 - (quad * 4 + r);
    int rel1 = rel0 + 16;
    bool m0 = t0dead || (rel0 < -WINDOW);
    bool m1 = (rel1 > 0);
    sc0[r] = m0 ? -INFINITY : s0[r] * 0.125f + slope * (float)rel0;
    sc1[r] = m1 ? -INFINITY : s1[r] * 0.125f + slope * (float)rel1;
  }
  float mx[4], sum[4], p0[4], p1[4];
#pragma unroll
  for (int r = 0; r < 4; r++) mx[r] = fmaxf(sc0[r], sc1[r]);
#pragma unroll
  for (int off = 8; off >= 1; off >>= 1)
#pragma unroll
    for (int r = 0; r < 4; r++) mx[r] = fmaxf(mx[r], __shfl_xor(mx[r], off));
#pragma unroll
  for (int r = 0; r < 4; r++) {
    p0[r] = __expf(sc0[r] - mx[r]);
    p1[r] = __expf(sc1[r] - mx[r]);
    sum[r] = p0[r] + p1[r];
  }
#pragma unroll
  for (int off = 8; off >= 1; off >>= 1)
#pragma unroll
    for (int r = 0; r < 4; r++) sum[r] += __shfl_xor(sum[r], off);

#pragma unroll
  for (int r = 0; r < 4; r++) {
    Ps[w][quad * 4 + r][col] = (bf16_t)p0[r];
    Ps[w][quad * 4 + r][16 + col] = (bf16_t)p1[r];
  }
  // no __syncthreads: Ps[w] is wave-private; DS ops in-order within a wave
  bf16x8 pf = *(const bf16x8*)(&Ps[w][col][quad * 8]);

  f32x4 o[4] = {};
#pragma unroll
  for (int nt = 0; nt < 4; nt++)
    o[nt] = __builtin_amdgcn_mfma_f32_16x16x32_bf16(pf, vf[nt], o[nt], 0, 0, 0);

#pragma unroll
  for (int nt = 0; nt < 4; nt++)
#pragma unroll
    for (int r = 0; r < 4; r++)
      y[(size_t)(rowg0 + quad * 4 + r) * 1024 + h * 64 + nt * 16 + col] =
          (bf16_t)(o[nt][r] / sum[r]);
}

extern "C" void kernel_launch(void* const* d_in, const int* in_sizes, int n_in,
                              void* d_out, int out_size, void* d_ws, size_t ws_size,
                              hipStream_t stream) {
  const float* x  = (const float*)d_in[0];
  const float* wq = (const float*)d_in[1];
  const float* wk = (const float*)d_in[2];
  const float* wv = (const float*)d_in[3];
  const float* wo = (const float*)d_in[4];
  const float* qw = (const float*)d_in[5];
  const float* kw = (const float*)d_in[6];
  float* out = (float*)d_out;

  const int M = 4096;  // B*L

  bf16_t* xb    = (bf16_t*)d_ws;
  bf16_t* wqkvb = xb + (size_t)M * DIM;        // [1536, 1024]
  bf16_t* wob   = wqkvb + (size_t)1536 * DIM;  // [1024, 1024]
  bf16_t* qkv   = wob + (size_t)DIM * DIM;     // [4096, 1536]
  bf16_t* yb    = qkv + (size_t)M * 1536;      // [4096, 1024]

  dim3 blk(256);
  f2bf_all<<<1703936 / 256, blk, 0, stream>>>(x, wq, wk, wv, wo, xb, wqkvb, wob);

  // QKV projection + fused RMSNorm: 768 blocks, XCD-swizzled (NBX=24, BYX=4)
  gemm_qkv_rms<<<768, blk, 0, stream>>>(xb, wqkvb, qkv, qw, kw, M, 1536, DIM);

  // attention: 256 blocks x 1024 threads, shared K/V staging
  attn_mfma<<<256, dim3(1024), 0, stream>>>(qkv, yb);

  // out projection: 512 blocks, XCD-swizzled (NBX=16, BYX=4)
  gemm_bf16<float, 16, 4><<<512, blk, 0, stream>>>(yb, wob, out, M, DIM, DIM);
}

// Round 12
// 126.227 us; speedup vs baseline: 1.4424x; 1.4424x over previous
//
#include <hip/hip_runtime.h>
#include <math.h>

#define DIM 1024
#define NH 16
#define NKV 4
#define HD 64
#define WINDOW 16
#define EPS 0.01f

typedef __bf16 bf16_t;
typedef bf16_t bf16x8 __attribute__((ext_vector_type(8)));
typedef bf16_t bf16x4 __attribute__((ext_vector_type(4)));
typedef float f32x4 __attribute__((ext_vector_type(4)));

// ---------------- fused fp32 -> bf16 conversion of all 5 tensors ----------------
__global__ __launch_bounds__(256) void f2bf_all(const float* __restrict__ x,
                                                const float* __restrict__ wq,
                                                const float* __restrict__ wk,
                                                const float* __restrict__ wv,
                                                const float* __restrict__ wo,
                                                bf16_t* __restrict__ xb,
                                                bf16_t* __restrict__ wqkvb,
                                                bf16_t* __restrict__ wob) {
  int i = blockIdx.x * blockDim.x + threadIdx.x;
  const float* src;
  bf16_t* dst;
  int off;
  if (i < 1048576) { src = x; dst = xb; off = i; }
  else if (i < 1310720) { src = wq; dst = wqkvb; off = i - 1048576; }
  else if (i < 1376256) { src = wk; dst = wqkvb + (size_t)1024 * DIM; off = i - 1310720; }
  else if (i < 1441792) { src = wv; dst = wqkvb + (size_t)1280 * DIM; off = i - 1376256; }
  else { src = wo; dst = wob; off = i - 1441792; }
  float4 f = ((const float4*)src)[off];
  bf16x4 o = {(bf16_t)f.x, (bf16_t)f.y, (bf16_t)f.z, (bf16_t)f.w};
  ((bf16x4*)dst)[off] = o;
}

// ========== 128(M)x64(N), BK=64, double-buffered swizzled-staging GEMM ========
// (R10 configuration — best verified. R11's B-direct-from-global regressed:
// compiler sinks B loads to uses, defeating prefetch; DMA staging can't be
// re-scheduled into the dependence chain and holds no VGPRs.)
// XCD-affinity swizzle: xcd = id&7 owns whole 128-row A-panels.
// LDS swizzle: row r, slot s holds global chunk kc=(s-r)&7; reader slot=(kc+r)&7.

#define GEMM_STAGE(buf, Ag, Bg)                                                 \
  {                                                                             \
    _Pragma("unroll")                                                           \
    for (int it = 0; it < 4; it++) {                                            \
      int c = it * 256 + t;                                                     \
      int r = c >> 3;                                                           \
      int kc = ((c & 7) - r) & 7;                                               \
      __builtin_amdgcn_global_load_lds(                                         \
          (const __attribute__((address_space(1))) void*)((Ag) + (size_t)r * K + kc * 8), \
          (__attribute__((address_space(3))) void*)(As[buf] + c * 8), 16, 0, 0); \
    }                                                                           \
    _Pragma("unroll")                                                           \
    for (int it = 0; it < 2; it++) {                                            \
      int c = it * 256 + t;                                                     \
      int r = c >> 3;                                                           \
      int kc = ((c & 7) - r) & 7;                                               \
      __builtin_amdgcn_global_load_lds(                                         \
          (const __attribute__((address_space(1))) void*)((Bg) + (size_t)r * K + kc * 8), \
          (__attribute__((address_space(3))) void*)(Bs[buf] + c * 8), 16, 0, 0); \
    }                                                                           \
  }

#define GEMM_DBUF_LOOP(Aptr, Bptr)                                              \
  {                                                                             \
    const bf16_t* Abase = Aptr + (size_t)row0 * K;                              \
    const bf16_t* Bbase = Bptr + (size_t)col0 * K;                              \
    GEMM_STAGE(0, Abase, Bbase)                                                 \
    const int nIter = K >> 6;                                                   \
    for (int ki = 0; ki < nIter; ki++) {                                        \
      __syncthreads();                                                          \
      if (ki + 1 < nIter)                                                       \
        GEMM_STAGE((ki + 1) & 1, Abase + (ki + 1) * 64, Bbase + (ki + 1) * 64)  \
      const bf16_t* Ab = As[ki & 1];                                            \
      const bf16_t* Bb = Bs[ki & 1];                                            \
      _Pragma("unroll")                                                         \
      for (int h = 0; h < 2; h++) {                                             \
        bf16x8 af[2], bfr[4];                                                   \
        _Pragma("unroll")                                                       \
        for (int mi = 0; mi < 2; mi++) af[mi] = *(const bf16x8*)(Ab + aoff[h][mi]); \
        _Pragma("unroll")                                                       \
        for (int ni = 0; ni < 4; ni++) bfr[ni] = *(const bf16x8*)(Bb + boff[h][ni]); \
        _Pragma("unroll")                                                       \
        for (int mi = 0; mi < 2; mi++)                                          \
          _Pragma("unroll")                                                     \
          for (int ni = 0; ni < 4; ni++)                                        \
            acc[mi][ni] = __builtin_amdgcn_mfma_f32_16x16x32_bf16(af[mi], bfr[ni], \
                                                                  acc[mi][ni], 0, 0, 0); \
      }                                                                         \
    }                                                                           \
  }

// NBX = N/64 column blocks; BYX = (M/128)/8 row-panels per XCD
#define GEMM_PROLOGUE(NBX, BYX)                                                 \
  const int t = threadIdx.x;                                                    \
  const int lane = t & 63;                                                      \
  const int wid = t >> 6;                                                       \
  const int xcd = blockIdx.x & 7;                                               \
  const int jj = blockIdx.x >> 3;                                               \
  const int bx = jj % (NBX);                                                    \
  const int row0 = (xcd * (BYX) + jj / (NBX)) * 128;                            \
  const int col0 = bx * 64;                                                     \
  const int wm = wid * 32;                                                      \
  const int lquad = lane >> 4;                                                  \
  const int lcol = lane & 15;                                                   \
  int aoff[2][2], boff[2][4];                                                   \
  _Pragma("unroll")                                                             \
  for (int h = 0; h < 2; h++) {                                                 \
    _Pragma("unroll")                                                           \
    for (int mi = 0; mi < 2; mi++) {                                            \
      int r = wm + mi * 16 + lcol;                                              \
      aoff[h][mi] = r * 64 + (((h * 4 + lquad) + r) & 7) * 8;                   \
    }                                                                           \
    _Pragma("unroll")                                                           \
    for (int ni = 0; ni < 4; ni++) {                                            \
      int r = ni * 16 + lcol;                                                   \
      boff[h][ni] = r * 64 + (((h * 4 + lquad) + r) & 7) * 8;                   \
    }                                                                           \
  }                                                                             \
  f32x4 acc[2][4] = {};

// ---------------- QKV GEMM with fused per-head RMSNorm epilogue ----------------
__global__ __launch_bounds__(256) void gemm_qkv_rms(const bf16_t* __restrict__ A,
                                                    const bf16_t* __restrict__ B,
                                                    bf16_t* __restrict__ C,
                                                    const float* __restrict__ qw,
                                                    const float* __restrict__ kw,
                                                    int M, int N, int K) {
  __shared__ bf16_t As[2][128 * 64];
  __shared__ bf16_t Bs[2][64 * 64];
  GEMM_PROLOGUE(24, 4)
  GEMM_DBUF_LOOP(A, B)

  // ---- fused RMSNorm epilogue: block's 64 cols == one head, wave-local rows
  const int hcol = bx;                   // 0..23
  const bool isv = (hcol >= 20);
  float wreg[4];
  if (!isv) {
    const float* wp = (hcol < 16) ? qw : kw;
#pragma unroll
    for (int ni = 0; ni < 4; ni++) wreg[ni] = wp[ni * 16 + lcol];
  }

#pragma unroll
  for (int mi = 0; mi < 2; mi++) {
#pragma unroll
    for (int r = 0; r < 4; r++) {
      float norm = 1.0f;
      if (!isv) {
        float ss = 0.0f;
#pragma unroll
        for (int ni = 0; ni < 4; ni++) ss += acc[mi][ni][r] * acc[mi][ni][r];
#pragma unroll
        for (int off = 8; off >= 1; off >>= 1) ss += __shfl_xor(ss, off);
        norm = rsqrtf(ss * (1.0f / 64.0f) + EPS);
      }
      size_t base = (size_t)(row0 + wm + mi * 16 + lquad * 4 + r) * N + col0 + lcol;
#pragma unroll
      for (int ni = 0; ni < 4; ni++) {
        float v = acc[mi][ni][r] * norm;
        if (!isv) v *= wreg[ni];
        C[base + ni * 16] = (bf16_t)v;
      }
    }
  }
}

// ---------------- bf16 MFMA GEMM (128x64, dbuf, XCD-swizzled) -----------------
template <typename CT, int NBX, int BYX>
__global__ __launch_bounds__(256) void gemm_bf16(const bf16_t* __restrict__ A,
                                                 const bf16_t* __restrict__ B,
                                                 CT* __restrict__ C,
                                                 int M, int N, int K) {
  __shared__ bf16_t As[2][128 * 64];
  __shared__ bf16_t Bs[2][64 * 64];
  GEMM_PROLOGUE(NBX, BYX)
  GEMM_DBUF_LOOP(A, B)

#pragma unroll
  for (int mi = 0; mi < 2; mi++)
#pragma unroll
    for (int ni = 0; ni < 4; ni++) {
      size_t base = (size_t)(row0 + wm + mi * 16 + lquad * 4) * N + col0 + ni * 16 + lcol;
#pragma unroll
      for (int r = 0; r < 4; r++)
        C[base + (size_t)r * N] = (CT)acc[mi][ni][r];
    }
}

// ---------------- MFMA banded ALiBi attention (shared K/V staging) -----------
#define LKP 72  // K row stride (keys x dims)
#define LVP 40  // VT / P row stride

__global__ __launch_bounds__(1024) void attn_mfma(const bf16_t* __restrict__ qkv,
                                                  bf16_t* __restrict__ y) {
  __shared__ bf16_t Ks[4][32][LKP];    // [kvh][key][dim]
  __shared__ bf16_t VTs[4][64][LVP];   // [kvh][dim][swizzled key]
  __shared__ bf16_t Ps[16][16][LVP];   // [wave][qrow][key]

  const int t = threadIdx.x;
  const int lane = t & 63;
  const int w = t >> 6;                // 0..15 = head
  const int b = blockIdx.x >> 7;
  const int i0loc = (blockIdx.x & 127) << 4;
  const int rowbase = b << 11;
  const int rowg0 = rowbase + i0loc;

  // ---- stage K and V once: thread t handles chunk t (kvh, key, 16B dim-chunk)
  {
    int kvh = t >> 8;
    int key = (t >> 3) & 31;
    int dc = t & 7;
    int jloc = i0loc - 16 + key;
    int rg = rowbase + (jloc < 0 ? 0 : jloc);
    const bf16_t* src = qkv + (size_t)rg * 1536 + 1024 + kvh * 64 + dc * 8;
    bf16x8 kval = *(const bf16x8*)src;
    *(bf16x8*)(&Ks[kvh][key][dc * 8]) = kval;
    bf16x8 vval = *(const bf16x8*)(src + 256);   // V is 256 elems after K
    int kslot = ((key >> 3) ^ (dc & 3)) * 8 + (key & 7);
#pragma unroll
    for (int e = 0; e < 8; e++) VTs[kvh][dc * 8 + e][kslot] = vval[e];
  }
  __syncthreads();

  const int col = lane & 15;
  const int quad = lane >> 4;
  const int h = w;
  const int kvh = w & 3;
  const float slope = exp2f(-0.5f * (float)(h + 1));

  bf16x8 kf[2][2];
#pragma unroll
  for (int kt = 0; kt < 2; kt++)
#pragma unroll
    for (int kc = 0; kc < 2; kc++)
      kf[kt][kc] = *(const bf16x8*)(&Ks[kvh][kt * 16 + col][kc * 32 + quad * 8]);
  bf16x8 vf[4];
#pragma unroll
  for (int nt = 0; nt < 4; nt++) {
    int dim = nt * 16 + col;
    int kchunk = quad ^ ((dim >> 3) & 3);
    vf[nt] = *(const bf16x8*)(&VTs[kvh][dim][kchunk * 8]);
  }

  const bf16_t* qrow = qkv + (size_t)(rowg0 + col) * 1536 + h * 64;
  bf16x8 qf0 = *(const bf16x8*)(qrow + quad * 8);
  bf16x8 qf1 = *(const bf16x8*)(qrow + 32 + quad * 8);

  f32x4 s0 = {}, s1 = {};
  s0 = __builtin_amdgcn_mfma_f32_16x16x32_bf16(qf0, kf[0][0], s0, 0, 0, 0);
  s0 = __builtin_amdgcn_mfma_f32_16x16x32_bf16(qf1, kf[0][1], s0, 0, 0, 0);
  s1 = __builtin_amdgcn_mfma_f32_16x16x32_bf16(qf0, kf[1][0], s1, 0, 0, 0);
  s1 = __builtin_amdgcn_mfma_f32_16x16x32_bf16(qf1, kf[1][1], s1, 0, 0, 0);

  const bool t0dead = (i0loc == 0);
  float sc0[4], sc1[4];
#pragma unroll
  for (int r = 0; r < 4; r++) {
    int rel0 = col - 16 - (quad * 4 + r);
    int rel1 = rel0 + 16;
    bool m0 = t0dead || (rel0 < -WINDOW);
    bool m1 = (rel1 > 0);
    sc0[r] = m0 ? -INFINITY : s0[r] * 0.125f + slope * (float)rel0;
    sc1[r] = m1 ? -INFINITY : s1[r] * 0.125f + slope * (float)rel1;
  }
  float mx[4], sum[4], p0[4], p1[4];
#pragma unroll
  for (int r = 0; r < 4; r++) mx[r] = fmaxf(sc0[r], sc1[r]);
#pragma unroll
  for (int off = 8; off >= 1; off >>= 1)
#pragma unroll
    for (int r = 0; r < 4; r++) mx[r] = fmaxf(mx[r], __shfl_xor(mx[r], off));
#pragma unroll
  for (int r = 0; r < 4; r++) {
    p0[r] = __expf(sc0[r] - mx[r]);
    p1[r] = __expf(sc1[r] - mx[r]);
    sum[r] = p0[r] + p1[r];
  }
#pragma unroll
  for (int off = 8; off >= 1; off >>= 1)
#pragma unroll
    for (int r = 0; r < 4; r++) sum[r] += __shfl_xor(sum[r], off);

#pragma unroll
  for (int r = 0; r < 4; r++) {
    Ps[w][quad * 4 + r][col] = (bf16_t)p0[r];
    Ps[w][quad * 4 + r][16 + col] = (bf16_t)p1[r];
  }
  // no __syncthreads: Ps[w] is wave-private; DS ops in-order within a wave
  bf16x8 pf = *(const bf16x8*)(&Ps[w][col][quad * 8]);

  f32x4 o[4] = {};
#pragma unroll
  for (int nt = 0; nt < 4; nt++)
    o[nt] = __builtin_amdgcn_mfma_f32_16x16x32_bf16(pf, vf[nt], o[nt], 0, 0, 0);

#pragma unroll
  for (int nt = 0; nt < 4; nt++)
#pragma unroll
    for (int r = 0; r < 4; r++)
      y[(size_t)(rowg0 + quad * 4 + r) * 1024 + h * 64 + nt * 16 + col] =
          (bf16_t)(o[nt][r] / sum[r]);
}

extern "C" void kernel_launch(void* const* d_in, const int* in_sizes, int n_in,
                              void* d_out, int out_size, void* d_ws, size_t ws_size,
                              hipStream_t stream) {
  const float* x  = (const float*)d_in[0];
  const float* wq = (const float*)d_in[1];
  const float* wk = (const float*)d_in[2];
  const float* wv = (const float*)d_in[3];
  const float* wo = (const float*)d_in[4];
  const float* qw = (const float*)d_in[5];
  const float* kw = (const float*)d_in[6];
  float* out = (float*)d_out;

  const int M = 4096;  // B*L

  bf16_t* xb    = (bf16_t*)d_ws;
  bf16_t* wqkvb = xb + (size_t)M * DIM;        // [1536, 1024]
  bf16_t* wob   = wqkvb + (size_t)1536 * DIM;  // [1024, 1024]
  bf16_t* qkv   = wob + (size_t)DIM * DIM;     // [4096, 1536]
  bf16_t* yb    = qkv + (size_t)M * 1536;      // [4096, 1024]

  dim3 blk(256);
  f2bf_all<<<1703936 / 256, blk, 0, stream>>>(x, wq, wk, wv, wo, xb, wqkvb, wob);

  // QKV projection + fused RMSNorm: 768 blocks, XCD-swizzled (NBX=24, BYX=4)
  gemm_qkv_rms<<<768, blk, 0, stream>>>(xb, wqkvb, qkv, qw, kw, M, 1536, DIM);

  // attention: 256 blocks x 1024 threads, shared K/V staging
  attn_mfma<<<256, dim3(1024), 0, stream>>>(qkv, yb);

  // out projection: 512 blocks, XCD-swizzled (NBX=16, BYX=4)
  gemm_bf16<float, 16, 4><<<512, blk, 0, stream>>>(yb, wob, out, M, DIM, DIM);
}